// Round 4
// baseline (294.436 us; speedup 1.0000x reference)
//
#include <hip/hip_runtime.h>
#include <math.h>

typedef unsigned short ushort_t;
typedef unsigned int   uint_t;
typedef __attribute__((ext_vector_type(8))) short bf16x8;
typedef __attribute__((ext_vector_type(4))) float f32x4;

#define NTOK 131072
#define MT   32       // tokens per block = per wave
#define TPB  64       // 1 wave per block; 4096 blocks; no barriers anywhere

// ws layout (ushort elems): hi array then lo array
#define OFF_KEY 0
#define OFF_VAL 4096      // contiguous after KEY -> combined k|v GEMM cols 0..7
#define OFF_T   8192      // 8 matrices of 4096 (p=0..6 T_W, p=7 = T_b)
#define OFF_D1  40960
#define OFF_D2  45056     // [32][64]
#define OFF_D3  47104     // [64][32]
#define WTOT    49152

// truncation split: hi = top16 bits (error captured exactly in lo),
// lo = bf16-trunc of remainder. total rep err ~2^-16 rel.
__device__ __forceinline__ void tsplit(float f, ushort_t& h, ushort_t& l) {
    uint_t u = __builtin_bit_cast(uint_t, f);
    h = (ushort_t)(u >> 16);
    float hf = __builtin_bit_cast(float, u & 0xffff0000u);
    l = (ushort_t)(__builtin_bit_cast(uint_t, f - hf) >> 16);
}
__device__ __forceinline__ uint_t packsplit(float f) {   // low16=hi, high16=lo
    uint_t u = __builtin_bit_cast(uint_t, f);
    float hf = __builtin_bit_cast(float, u & 0xffff0000u);
    uint_t lu = __builtin_bit_cast(uint_t, f - hf);
    return (u >> 16) | (lu & 0xffff0000u);
}
__device__ __forceinline__ void unpack8(uint4 a, uint4 b, bf16x8& h, bf16x8& l) {
    uint_t u[8] = {a.x, a.y, a.z, a.w, b.x, b.y, b.z, b.w};
    bf16x8 hh, ll;
#pragma unroll
    for (int j = 0; j < 8; ++j) {
        hh[j] = (short)(u[j] & 0xffffu);
        ll[j] = (short)(u[j] >> 16);
    }
    h = hh; l = ll;
}

__device__ __forceinline__ f32x4 mfma3(bf16x8 ah, bf16x8 al, bf16x8 bh, bf16x8 bl, f32x4 c) {
    c = __builtin_amdgcn_mfma_f32_16x16x32_bf16(al, bh, c, 0, 0, 0);
    c = __builtin_amdgcn_mfma_f32_16x16x32_bf16(ah, bl, c, 0, 0, 0);
    c = __builtin_amdgcn_mfma_f32_16x16x32_bf16(ah, bh, c, 0, 0, 0);
    return c;
}

struct Bfrag { bf16x8 h0, h1, l0, l1; };
__device__ __forceinline__ Bfrag loadB(const ushort_t* __restrict__ bh,
                                       const ushort_t* __restrict__ bl, int off) {
    Bfrag b;
    b.h0 = *(const bf16x8*)(bh + off);
    b.h1 = *(const bf16x8*)(bh + off + 32);
    b.l0 = *(const bf16x8*)(bl + off);
    b.l1 = *(const bf16x8*)(bl + off + 32);
    return b;
}

// K=64 GEMM, single row-tile
template<int NC>
__device__ __forceinline__ void gemm1rt(const ushort_t* __restrict__ bh,
                                        const ushort_t* __restrict__ bl,
                                        int l15, int quad,
                                        const bf16x8 ah[2], const bf16x8 al[2],
                                        f32x4 acc[NC])
{
#pragma unroll
    for (int c = 0; c < NC; ++c) {
        int off = (16 * c + l15) * 64 + quad * 8;
        Bfrag b = loadB(bh, bl, off);
        f32x4 a = acc[c];
        a = mfma3(ah[0], al[0], b.h0, b.l0, a);
        a = mfma3(ah[1], al[1], b.h1, b.l1, a);
        acc[c] = a;
    }
}
// K=64 GEMM, B shared across both row-tiles
template<int NC>
__device__ __forceinline__ void gemm2rt(const ushort_t* __restrict__ bh,
                                        const ushort_t* __restrict__ bl,
                                        int l15, int quad,
                                        const bf16x8 ah[2][2], const bf16x8 al[2][2],
                                        f32x4 acc[2][NC])
{
#pragma unroll
    for (int c = 0; c < NC; ++c) {
        int off = (16 * c + l15) * 64 + quad * 8;
        Bfrag b = loadB(bh, bl, off);
#pragma unroll
        for (int rt = 0; rt < 2; ++rt) {
            f32x4 a = acc[rt][c];
            a = mfma3(ah[rt][0], al[rt][0], b.h0, b.l0, a);
            a = mfma3(ah[rt][1], al[rt][1], b.h1, b.l1, a);
            acc[rt][c] = a;
        }
    }
}

// ---------------- prep: split+transpose all weights into ws (bf16 hi/lo) ----
__global__ __launch_bounds__(256)
void prep_w(const float* __restrict__ keyW, const float* __restrict__ valW,
            const float* __restrict__ TW,   const float* __restrict__ TB,
            const float* __restrict__ d1W,  const float* __restrict__ d2W,
            const float* __restrict__ d3W,
            ushort_t* __restrict__ whi, ushort_t* __restrict__ wlo)
{
    int idx = blockIdx.x * 256 + threadIdx.x;
    if (idx >= WTOT) return;
    float src;
    if (idx < OFF_VAL) {
        int r = idx - OFF_KEY, n = r >> 6, j = r & 63;
        src = keyW[j * 64 + n];
    } else if (idx < OFF_T) {
        int r = idx - OFF_VAL, n = r >> 6, j = r & 63;
        src = valW[j * 64 + n];
    } else if (idx < OFF_D1) {
        int r = idx - OFF_T, p = r >> 12, q = r & 4095;
        src = (p < 7) ? TW[p * 4096 + q] : TB[q];
    } else if (idx < OFF_D2) {
        int r = idx - OFF_D1, n = r >> 6, j = r & 63;
        src = d1W[j * 64 + n];
    } else if (idx < OFF_D3) {
        int r = idx - OFF_D2, n = r >> 6, j = r & 63;
        src = d2W[j * 32 + n];
    } else {
        int r = idx - OFF_D3, n = r >> 5, j = r & 31;
        src = d3W[j * 64 + n];
    }
    ushort_t h, l;
    tsplit(src, h, l);
    whi[idx] = h;
    wlo[idx] = l;
}

// ---------------- main fused kernel: 1 wave/block, zero barriers ------------
__global__ __launch_bounds__(TPB, 4)
void fused_mfma(const float* __restrict__ kv_in, const float* __restrict__ q_in,
                const float* __restrict__ keyB,  const float* __restrict__ valB,
                const float* __restrict__ d1B,   const float* __restrict__ d2B,
                const float* __restrict__ d3B,   const float* __restrict__ scale_p,
                const ushort_t* __restrict__ whi, const ushort_t* __restrict__ wlo,
                float* __restrict__ out)
{
    // Rly holds packed(hi|lo): first the staged kv tile, later the x/h relays.
    // Row lifetimes are disjoint where they overlap (rt=0 x-write rows 0..15 vs
    // rt=1 kv-read rows 16..31); same-wave LDS ordering via compiler lgkmcnt.
    __shared__ __align__(16) uint_t Rly[MT][68];   // 8704 B
    __shared__ __align__(16) float  Qs[8][MT];     // 1024 B
    // total 9728 B -> 16 blocks/CU; VGPR<=128 -> 4 waves/SIMD

    const int lane = threadIdx.x;
    const int quad = lane >> 4, l15 = lane & 15;
    const long t0  = (long)blockIdx.x * MT;

    // ---- coalesced kv staging -> packed split in LDS ----
    {
        const int r = lane >> 1, half = lane & 1;
        const float4* p4 = (const float4*)(kv_in + (t0 + r) * 64 + half * 32);
        uint_t* dst = &Rly[r][half * 32];
#pragma unroll
        for (int b = 0; b < 8; ++b) {
            float4 f = p4[b];
            uint4 pk;
            pk.x = packsplit(f.x); pk.y = packsplit(f.y);
            pk.z = packsplit(f.z); pk.w = packsplit(f.w);
            *(uint4*)(dst + b * 4) = pk;
        }
    }
    // ---- q' -> Qs ----
    if (lane < MT) {
        const float* qp = q_in + (t0 + lane) * 7;
#pragma unroll
        for (int p = 0; p < 7; ++p) Qs[p][lane] = qp[p];
        Qs[7][lane] = 1.0f;
    }

    float kb[4], vb[4];
#pragma unroll
    for (int c = 0; c < 4; ++c) { kb[c] = keyB[16 * c + l15]; vb[c] = valB[16 * c + l15]; }
    const float sc = scale_p[0];

    // ================= front section: per row-tile (keeps VGPR low) ========
#pragma unroll 1
    for (int rt = 0; rt < 2; ++rt) {
        // A-fragments for this row-tile from LDS
        bf16x8 ah[2], al[2];
#pragma unroll
        for (int ks = 0; ks < 2; ++ks) {
            const uint4* pr = (const uint4*)&Rly[16 * rt + l15][ks * 32 + quad * 8];
            unpack8(pr[0], pr[1], ah[ks], al[ks]);
        }

        // ---- T stage: qacc = sum_p q'_p * (KV @ T_p^T) ----
        f32x4 qacc[4] = {};
#pragma unroll 2
        for (int p = 0; p < 8; ++p) {
            f32x4 tmp[4] = {};
            gemm1rt<4>(whi + OFF_T + p * 4096, wlo + OFF_T + p * 4096,
                       l15, quad, ah, al, tmp);
            f32x4 qp = *(const f32x4*)&Qs[p][16 * rt + quad * 4];
#pragma unroll
            for (int c = 0; c < 4; ++c)
#pragma unroll
                for (int e = 0; e < 4; ++e)
                    qacc[c][e] = fmaf(qp[e], tmp[c][e], qacc[c][e]);
        }

        // ---- combined k|v GEMM (key cols 0..3, val cols 4..7) ----
        f32x4 kv8[8] = {};
        gemm1rt<8>(whi + OFF_KEY, wlo + OFF_KEY, l15, quad, ah, al, kv8);

        // ---- elementwise: softmax(v*sc), att=q*k, L2-normalize, x relay ----
        f32x4 sv[4], mx;
#pragma unroll
        for (int e = 0; e < 4; ++e) mx[e] = -3.4e38f;
#pragma unroll
        for (int c = 0; c < 4; ++c) {
            sv[c] = (kv8[4 + c] + vb[c]) * sc;
#pragma unroll
            for (int e = 0; e < 4; ++e) mx[e] = fmaxf(mx[e], sv[c][e]);
        }
#pragma unroll
        for (int m = 1; m < 16; m <<= 1)
#pragma unroll
            for (int e = 0; e < 4; ++e) mx[e] = fmaxf(mx[e], __shfl_xor(mx[e], m, 64));
        f32x4 se = {};
#pragma unroll
        for (int c = 0; c < 4; ++c) {
#pragma unroll
            for (int e = 0; e < 4; ++e) sv[c][e] = __expf(sv[c][e] - mx[e]);
            se += sv[c];
        }
#pragma unroll
        for (int m = 1; m < 16; m <<= 1)
#pragma unroll
            for (int e = 0; e < 4; ++e) se[e] += __shfl_xor(se[e], m, 64);
        f32x4 nr = {};
        f32x4 at[4];
#pragma unroll
        for (int c = 0; c < 4; ++c) {
            at[c] = qacc[c] * (kv8[c] + kb[c]);
            nr += at[c] * at[c];
        }
#pragma unroll
        for (int m = 1; m < 16; m <<= 1)
#pragma unroll
            for (int e = 0; e < 4; ++e) nr[e] += __shfl_xor(nr[e], m, 64);
        f32x4 fac;
#pragma unroll
        for (int e = 0; e < 4; ++e)
            fac[e] = 1.0f / (fmaxf(sqrtf(nr[e]), 1e-8f) * se[e]);
#pragma unroll
        for (int c = 0; c < 4; ++c)
#pragma unroll
            for (int e = 0; e < 4; ++e)
                Rly[16 * rt + quad * 4 + e][16 * c + l15] =
                    packsplit(at[c][e] * sv[c][e] * fac[e]);
    }

    // ================= MLP head (both row-tiles) ============================
    bf16x8 xh[2][2], xl[2][2];
#pragma unroll
    for (int rt = 0; rt < 2; ++rt)
#pragma unroll
        for (int ks = 0; ks < 2; ++ks) {
            const uint4* pr = (const uint4*)&Rly[16 * rt + l15][ks * 32 + quad * 8];
            unpack8(pr[0], pr[1], xh[rt][ks], xl[rt][ks]);
        }
    f32x4 h1a[2][4] = {};
    gemm2rt<4>(whi + OFF_D1, wlo + OFF_D1, l15, quad, xh, xl, h1a);
    {
        float b1[4];
#pragma unroll
        for (int c = 0; c < 4; ++c) b1[c] = d1B[16 * c + l15];
#pragma unroll
        for (int rt = 0; rt < 2; ++rt)
#pragma unroll
            for (int c = 0; c < 4; ++c)
#pragma unroll
                for (int e = 0; e < 4; ++e)
                    Rly[16 * rt + quad * 4 + e][16 * c + l15] =
                        packsplit(fmaxf(h1a[rt][c][e] + b1[c], 0.f));
    }

#pragma unroll
    for (int rt = 0; rt < 2; ++rt)
#pragma unroll
        for (int ks = 0; ks < 2; ++ks) {
            const uint4* pr = (const uint4*)&Rly[16 * rt + l15][ks * 32 + quad * 8];
            unpack8(pr[0], pr[1], xh[rt][ks], xl[rt][ks]);
        }
    f32x4 h2a[2][2] = {};
    gemm2rt<2>(whi + OFF_D2, wlo + OFF_D2, l15, quad, xh, xl, h2a);
    {
        float b2[2];
#pragma unroll
        for (int c = 0; c < 2; ++c) b2[c] = d2B[16 * c + l15];
#pragma unroll
        for (int rt = 0; rt < 2; ++rt)
#pragma unroll
            for (int c = 0; c < 2; ++c)
#pragma unroll
                for (int e = 0; e < 4; ++e)
                    Rly[16 * rt + quad * 4 + e][16 * c + l15] =
                        packsplit(fmaxf(h2a[rt][c][e] + b2[c], 0.f));
    }

    // ---- d3: out = h2 @ d3 + b3 (K=32) ----
    bf16x8 a3h[2], a3l[2];
#pragma unroll
    for (int rt = 0; rt < 2; ++rt) {
        const uint4* pr = (const uint4*)&Rly[16 * rt + l15][quad * 8];
        unpack8(pr[0], pr[1], a3h[rt], a3l[rt]);
    }
    float b3[4];
#pragma unroll
    for (int c = 0; c < 4; ++c) b3[c] = d3B[16 * c + l15];
#pragma unroll
    for (int c = 0; c < 4; ++c) {
        int off = (16 * c + l15) * 32 + quad * 8;
        bf16x8 bh = *(const bf16x8*)(whi + OFF_D3 + off);
        bf16x8 bl = *(const bf16x8*)(wlo + OFF_D3 + off);
#pragma unroll
        for (int rt = 0; rt < 2; ++rt) {
            f32x4 a = {};
            a = mfma3(a3h[rt], a3l[rt], bh, bl, a);
            float* op = out + (t0 + 16 * rt + quad * 4) * 64 + 16 * c + l15;
#pragma unroll
            for (int e = 0; e < 4; ++e) op[e * 64] = a[e] + b3[c];
        }
    }
}

extern "C" void kernel_launch(void* const* d_in, const int* in_sizes, int n_in,
                              void* d_out, int out_size, void* d_ws, size_t ws_size,
                              hipStream_t stream) {
    (void)in_sizes; (void)n_in; (void)out_size; (void)ws_size;
    const float* kv_in = (const float*)d_in[0];
    const float* q_in  = (const float*)d_in[1];
    const float* keyW  = (const float*)d_in[2];
    const float* keyB  = (const float*)d_in[3];
    const float* valW  = (const float*)d_in[4];
    const float* valB  = (const float*)d_in[5];
    const float* TW    = (const float*)d_in[6];
    const float* TB    = (const float*)d_in[7];
    const float* d1W   = (const float*)d_in[8];
    const float* d1B   = (const float*)d_in[9];
    const float* d2W   = (const float*)d_in[10];
    const float* d2B   = (const float*)d_in[11];
    const float* d3W   = (const float*)d_in[12];
    const float* d3B   = (const float*)d_in[13];
    const float* scale = (const float*)d_in[14];
    ushort_t* whi = (ushort_t*)d_ws;
    ushort_t* wlo = whi + WTOT;
    float* outp = (float*)d_out;

    prep_w<<<(WTOT + 255) / 256, 256, 0, stream>>>(keyW, valW, TW, TB, d1W, d2W, d3W, whi, wlo);
    fused_mfma<<<NTOK / MT, TPB, 0, stream>>>(kv_in, q_in, keyB, valB,
                                              d1B, d2B, d3B, scale, whi, wlo, outp);
}

// Round 5
// 180.721 us; speedup vs baseline: 1.6292x; 1.6292x over previous
//
#include <hip/hip_runtime.h>
#include <math.h>

typedef unsigned short ushort_t;
typedef _Float16 f16_t;
typedef __attribute__((ext_vector_type(8))) _Float16 f16x8;
typedef __attribute__((ext_vector_type(4))) float f32x4;

#define NTOK 131072
#define MT   128      // tokens per block
#define TPB  256      // 4 waves; each wave owns 32 tokens end-to-end; ZERO barriers
#define RPAD 76       // relay row pad (fp16 elems): 38 dwords/row -> conflict-free frag reads

// ws layout (f16 elems)
#define OFF_KEY 0
#define OFF_VAL 4096      // contiguous after KEY
#define OFF_T   8192      // 8 matrices of 4096 (p=0..6 T_W, p=7 = T_b)
#define OFF_D1  40960
#define OFF_D2  45056     // [32][64]
#define OFF_D3  47104     // [64][32]
#define WTOT    49152     // 96 KB fp16 total -> L2-resident

__device__ __forceinline__ f32x4 mfma1(f16x8 a, f16x8 b, f32x4 c) {
    return __builtin_amdgcn_mfma_f32_16x16x32_f16(a, b, c, 0, 0, 0);
}

struct Bfrag { f16x8 h0, h1; };
__device__ __forceinline__ Bfrag loadB(const f16_t* __restrict__ b, int off) {
    Bfrag r;
    r.h0 = *(const f16x8*)(b + off);
    r.h1 = *(const f16x8*)(b + off + 32);
    return r;
}

// K=64 GEMM, single row-tile
template<int NC>
__device__ __forceinline__ void gemm1rt(const f16_t* __restrict__ bw,
                                        int l15, int quad,
                                        const f16x8 ah[2], f32x4 acc[NC])
{
#pragma unroll
    for (int c = 0; c < NC; ++c) {
        Bfrag b = loadB(bw, (16 * c + l15) * 64 + quad * 8);
        f32x4 a = acc[c];
        a = mfma1(ah[0], b.h0, a);
        a = mfma1(ah[1], b.h1, a);
        acc[c] = a;
    }
}
// K=64 GEMM, B shared across both row-tiles
template<int NC>
__device__ __forceinline__ void gemm2rt(const f16_t* __restrict__ bw,
                                        int l15, int quad,
                                        const f16x8 ah[2][2], f32x4 acc[2][NC])
{
#pragma unroll
    for (int c = 0; c < NC; ++c) {
        Bfrag b = loadB(bw, (16 * c + l15) * 64 + quad * 8);
#pragma unroll
        for (int rt = 0; rt < 2; ++rt) {
            f32x4 a = acc[rt][c];
            a = mfma1(ah[rt][0], b.h0, a);
            a = mfma1(ah[rt][1], b.h1, a);
            acc[rt][c] = a;
        }
    }
}

// ---------------- prep: transpose all weights into ws as fp16 --------------
__global__ __launch_bounds__(256)
void prep_w(const float* __restrict__ keyW, const float* __restrict__ valW,
            const float* __restrict__ TW,   const float* __restrict__ TB,
            const float* __restrict__ d1W,  const float* __restrict__ d2W,
            const float* __restrict__ d3W,  f16_t* __restrict__ wsf)
{
    int idx = blockIdx.x * 256 + threadIdx.x;
    if (idx >= WTOT) return;
    float src;
    if (idx < OFF_VAL) {
        int r = idx - OFF_KEY, n = r >> 6, j = r & 63;
        src = keyW[j * 64 + n];
    } else if (idx < OFF_T) {
        int r = idx - OFF_VAL, n = r >> 6, j = r & 63;
        src = valW[j * 64 + n];
    } else if (idx < OFF_D1) {
        int r = idx - OFF_T, p = r >> 12, q = r & 4095;
        src = (p < 7) ? TW[p * 4096 + q] : TB[q];
    } else if (idx < OFF_D2) {
        int r = idx - OFF_D1, n = r >> 6, j = r & 63;
        src = d1W[j * 64 + n];
    } else if (idx < OFF_D3) {
        int r = idx - OFF_D2, n = r >> 6, j = r & 63;
        src = d2W[j * 32 + n];
    } else {
        int r = idx - OFF_D3, n = r >> 5, j = r & 31;
        src = d3W[j * 64 + n];
    }
    wsf[idx] = (f16_t)src;
}

// ---------------- main fused kernel: 4 waves, zero barriers ----------------
__global__ __launch_bounds__(TPB, 4)
void fused_mfma(const float* __restrict__ kv_in, const float* __restrict__ q_in,
                const float* __restrict__ keyB,  const float* __restrict__ valB,
                const float* __restrict__ d1B,   const float* __restrict__ d2B,
                const float* __restrict__ d3B,   const float* __restrict__ scale_p,
                const f16_t* __restrict__ wsf,   float* __restrict__ out)
{
    // Rly: fp16 staging of kv, later x/h relays. All accesses wave-private in
    // row space (wave w touches only rows [32w,32w+32)) -> no barriers.
    __shared__ __align__(16) f16_t Rly[MT][RPAD];   // 19456 B
    __shared__ __align__(16) float Qs[8][MT];       // 4096 B  -> 23.5 KB total

    const int tid  = threadIdx.x;
    const int wv   = tid >> 6, lane = tid & 63;
    const int quad = lane >> 4, l15 = lane & 15;
    const int RB   = wv * 32;
    const long t0  = (long)blockIdx.x * MT;

    // ---- coalesced kv staging -> fp16 in LDS (wave-private rows) ----
    {
        const int r = RB + (lane >> 1), half = lane & 1;
        const float4* p4 = (const float4*)(kv_in + (t0 + r) * 64 + half * 32);
        f16_t* dst = &Rly[r][half * 32];
#pragma unroll
        for (int b = 0; b < 4; ++b) {
            float4 f0 = p4[2 * b], f1 = p4[2 * b + 1];
            f16x8 h;
            h[0] = (f16_t)f0.x; h[1] = (f16_t)f0.y; h[2] = (f16_t)f0.z; h[3] = (f16_t)f0.w;
            h[4] = (f16_t)f1.x; h[5] = (f16_t)f1.y; h[6] = (f16_t)f1.z; h[7] = (f16_t)f1.w;
            *(f16x8*)(dst + 8 * b) = h;
        }
    }
    // ---- q' -> Qs (wave-private cols) ----
    if (lane < 32) {
        const float* qp = q_in + (t0 + RB + lane) * 7;
#pragma unroll
        for (int p = 0; p < 7; ++p) Qs[p][RB + lane] = qp[p];
        Qs[7][RB + lane] = 1.0f;
    }

    float kb[4], vb[4];
#pragma unroll
    for (int c = 0; c < 4; ++c) { kb[c] = keyB[16 * c + l15]; vb[c] = valB[16 * c + l15]; }
    const float sc = scale_p[0];

    // ---- A-fragments (kv) for both row-tiles ----
    f16x8 ah[2][2];
#pragma unroll
    for (int rt = 0; rt < 2; ++rt)
#pragma unroll
        for (int ks = 0; ks < 2; ++ks)
            ah[rt][ks] = *(const f16x8*)&Rly[RB + 16 * rt + l15][ks * 32 + quad * 8];

    // ---- T stage (2rt, T weights loaded once): q = sum_p q'_p*(KV @ T_p^T) ----
    f32x4 qacc[2][4] = {};
#pragma unroll 2
    for (int p = 0; p < 8; ++p) {
        f32x4 tmp[2][4] = {};
        gemm2rt<4>(wsf + OFF_T + p * 4096, l15, quad, ah, tmp);
        f32x4 qp0 = *(const f32x4*)&Qs[p][RB + quad * 4];
        f32x4 qp1 = *(const f32x4*)&Qs[p][RB + 16 + quad * 4];
#pragma unroll
        for (int c = 0; c < 4; ++c)
#pragma unroll
            for (int e = 0; e < 4; ++e) {
                qacc[0][c][e] = fmaf(qp0[e], tmp[0][c][e], qacc[0][c][e]);
                qacc[1][c][e] = fmaf(qp1[e], tmp[1][c][e], qacc[1][c][e]);
            }
    }

    // ---- per row-tile: combined k|v GEMM + elementwise + x relay ----
#pragma unroll 1
    for (int rt = 0; rt < 2; ++rt) {
        f32x4 kv8[8] = {};
        gemm1rt<8>(wsf + OFF_KEY, l15, quad, ah[rt], kv8);

        f32x4 sv[4], mx;
#pragma unroll
        for (int e = 0; e < 4; ++e) mx[e] = -3.4e38f;
#pragma unroll
        for (int c = 0; c < 4; ++c) {
            sv[c] = (kv8[4 + c] + vb[c]) * sc;
#pragma unroll
            for (int e = 0; e < 4; ++e) mx[e] = fmaxf(mx[e], sv[c][e]);
        }
#pragma unroll
        for (int m = 1; m < 16; m <<= 1)
#pragma unroll
            for (int e = 0; e < 4; ++e) mx[e] = fmaxf(mx[e], __shfl_xor(mx[e], m, 64));
        f32x4 se = {};
#pragma unroll
        for (int c = 0; c < 4; ++c) {
#pragma unroll
            for (int e = 0; e < 4; ++e) sv[c][e] = __expf(sv[c][e] - mx[e]);
            se += sv[c];
        }
#pragma unroll
        for (int m = 1; m < 16; m <<= 1)
#pragma unroll
            for (int e = 0; e < 4; ++e) se[e] += __shfl_xor(se[e], m, 64);
        f32x4 nr = {};
        f32x4 at[4];
#pragma unroll
        for (int c = 0; c < 4; ++c) {
            at[c] = qacc[rt][c] * (kv8[c] + kb[c]);
            nr += at[c] * at[c];
        }
#pragma unroll
        for (int m = 1; m < 16; m <<= 1)
#pragma unroll
            for (int e = 0; e < 4; ++e) nr[e] += __shfl_xor(nr[e], m, 64);
        f32x4 fac;
#pragma unroll
        for (int e = 0; e < 4; ++e)
            fac[e] = 1.0f / (fmaxf(sqrtf(nr[e]), 1e-8f) * se[e]);
#pragma unroll
        for (int c = 0; c < 4; ++c)
#pragma unroll
            for (int e = 0; e < 4; ++e)
                Rly[RB + 16 * rt + quad * 4 + e][16 * c + l15] =
                    (f16_t)(at[c][e] * sv[c][e] * fac[e]);
    }

    // ---- d1: h1 = relu(x @ d1 + b1) ----
    f16x8 xh[2][2];
#pragma unroll
    for (int rt = 0; rt < 2; ++rt)
#pragma unroll
        for (int ks = 0; ks < 2; ++ks)
            xh[rt][ks] = *(const f16x8*)&Rly[RB + 16 * rt + l15][ks * 32 + quad * 8];
    f32x4 h1a[2][4] = {};
    gemm2rt<4>(wsf + OFF_D1, l15, quad, xh, h1a);
    {
        float b1[4];
#pragma unroll
        for (int c = 0; c < 4; ++c) b1[c] = d1B[16 * c + l15];
#pragma unroll
        for (int rt = 0; rt < 2; ++rt)
#pragma unroll
            for (int c = 0; c < 4; ++c)
#pragma unroll
                for (int e = 0; e < 4; ++e)
                    Rly[RB + 16 * rt + quad * 4 + e][16 * c + l15] =
                        (f16_t)fmaxf(h1a[rt][c][e] + b1[c], 0.f);
    }

    // ---- d2: h2 = relu(h1 @ d2 + b2), 32 cols ----
#pragma unroll
    for (int rt = 0; rt < 2; ++rt)
#pragma unroll
        for (int ks = 0; ks < 2; ++ks)
            xh[rt][ks] = *(const f16x8*)&Rly[RB + 16 * rt + l15][ks * 32 + quad * 8];
    f32x4 h2a[2][2] = {};
    gemm2rt<2>(wsf + OFF_D2, l15, quad, xh, h2a);
    {
        float b2[2];
#pragma unroll
        for (int c = 0; c < 2; ++c) b2[c] = d2B[16 * c + l15];
#pragma unroll
        for (int rt = 0; rt < 2; ++rt)
#pragma unroll
            for (int c = 0; c < 2; ++c)
#pragma unroll
                for (int e = 0; e < 4; ++e)
                    Rly[RB + 16 * rt + quad * 4 + e][16 * c + l15] =
                        (f16_t)fmaxf(h2a[rt][c][e] + b2[c], 0.f);
    }

    // ---- d3: out = h2 @ d3 + b3 (K=32) ----
    f16x8 a3[2];
#pragma unroll
    for (int rt = 0; rt < 2; ++rt)
        a3[rt] = *(const f16x8*)&Rly[RB + 16 * rt + l15][quad * 8];
    float b3[4];
#pragma unroll
    for (int c = 0; c < 4; ++c) b3[c] = d3B[16 * c + l15];
#pragma unroll
    for (int c = 0; c < 4; ++c) {
        f16x8 bw = *(const f16x8*)(wsf + OFF_D3 + (16 * c + l15) * 32 + quad * 8);
#pragma unroll
        for (int rt = 0; rt < 2; ++rt) {
            f32x4 a = {};
            a = mfma1(a3[rt], bw, a);
            float* op = out + (t0 + RB + 16 * rt + quad * 4) * 64 + 16 * c + l15;
#pragma unroll
            for (int e = 0; e < 4; ++e) op[e * 64] = a[e] + b3[c];
        }
    }
}

extern "C" void kernel_launch(void* const* d_in, const int* in_sizes, int n_in,
                              void* d_out, int out_size, void* d_ws, size_t ws_size,
                              hipStream_t stream) {
    (void)in_sizes; (void)n_in; (void)out_size; (void)ws_size;
    const float* kv_in = (const float*)d_in[0];
    const float* q_in  = (const float*)d_in[1];
    const float* keyW  = (const float*)d_in[2];
    const float* keyB  = (const float*)d_in[3];
    const float* valW  = (const float*)d_in[4];
    const float* valB  = (const float*)d_in[5];
    const float* TW    = (const float*)d_in[6];
    const float* TB    = (const float*)d_in[7];
    const float* d1W   = (const float*)d_in[8];
    const float* d1B   = (const float*)d_in[9];
    const float* d2W   = (const float*)d_in[10];
    const float* d2B   = (const float*)d_in[11];
    const float* d3W   = (const float*)d_in[12];
    const float* d3B   = (const float*)d_in[13];
    const float* scale = (const float*)d_in[14];
    f16_t* wsf = (f16_t*)d_ws;
    float* outp = (float*)d_out;

    prep_w<<<(WTOT + 255) / 256, 256, 0, stream>>>(keyW, valW, TW, TB, d1W, d2W, d3W, wsf);
    fused_mfma<<<NTOK / MT, TPB, 0, stream>>>(kv_in, q_in, keyB, valB,
                                              d1B, d2B, d3B, scale, wsf, outp);
}